// Round 6
// baseline (160.110 us; speedup 1.0000x reference)
//
#include <hip/hip_runtime.h>
#include <math.h>

#define BLOCK 64
#define BATCH 16384
#define EPB 8      // elements per block (one wave = 8 elements x 8 roles)
#define EP 11      // element-dim stride (8 elems + pad) for per-element LDS
#define NDOF 7
#define ACTION_RANGE 50.0f
#define MAX_VEL 20.0f
#define HSTEP 0.1f

__device__ __forceinline__ void mat3_mul(float* C, const float* A, const float* B) {
#pragma unroll
  for (int r = 0; r < 3; r++) {
#pragma unroll
    for (int c = 0; c < 3; c++) {
      C[r*3+c] = A[r*3+0]*B[0*3+c] + A[r*3+1]*B[1*3+c] + A[r*3+2]*B[2*3+c];
    }
  }
}

__device__ __forceinline__ void mat3_vec(float* y, const float* A, const float* x) {
#pragma unroll
  for (int r = 0; r < 3; r++)
    y[r] = A[r*3+0]*x[0] + A[r*3+1]*x[1] + A[r*3+2]*x[2];
}

__device__ __forceinline__ void mat3T_vec(float* y, const float* A, const float* x) {
#pragma unroll
  for (int r = 0; r < 3; r++)
    y[r] = A[0*3+r]*x[0] + A[1*3+r]*x[1] + A[2*3+r]*x[2];
}

__device__ __forceinline__ void cross3(float* y, const float* a, const float* b) {
  y[0] = a[1]*b[2] - a[2]*b[1];
  y[1] = a[2]*b[0] - a[0]*b[2];
  y[2] = a[0]*b[1] - a[1]*b[0];
}

// R = I + s*W + (1-c)*W^2 ; p = (th*I + (1-c)*W + (th-s)*W^2) v
__device__ __forceinline__ void exp_se3(const float* A6, float th, float* R, float* p) {
  float w0 = A6[0], w1 = A6[1], w2 = A6[2];
  float s, c;
  sincosf(th, &s, &c);
  float omc = 1.0f - c, tms = th - s;
  float W[9]  = {0.f, -w2, w1,  w2, 0.f, -w0,  -w1, w0, 0.f};
  float W2[9];
  mat3_mul(W2, W, W);
#pragma unroll
  for (int k = 0; k < 9; k++) R[k] = s*W[k] + omc*W2[k];
  R[0] += 1.f; R[4] += 1.f; R[8] += 1.f;
  float G[9];
#pragma unroll
  for (int k = 0; k < 9; k++) G[k] = omc*W[k] + tms*W2[k];
  G[0] += th; G[4] += th; G[8] += th;
  mat3_vec(p, G, A6 + 3);
}

// python-style mod: a - floor(a/y)*y  (result in [0,y))
__device__ __forceinline__ float wrap_pi(float x) {
  const float PI_F   = 3.14159265358979323846f;
  const float TWO_PI = 6.28318530717958647692f;
  float a = x + PI_F;
  float r = a - floorf(a * (1.0f / TWO_PI)) * TWO_PI;
  return r - PI_F;
}

// 8 lanes per element: role r = lane&7, element slot e = lane>>3.
// R5 post-mortem: phase C's 42-float X history + unroll hoisting kept the
// allocator at the 128-VGPR tier with ~120 MB/dispatch scratch spills.
// R6: (a) mass matrix via direct sum M_ij = sum_k X_ki^T G_k X_kj with only
// the CURRENT X per lane (cross-lane via __shfl, triangular unroll) -> no
// history, no backward sweep; (b) amdgpu_waves_per_eu(2,2): grid caps at
// 2 waves/EU anyway, so let the allocator use up to 256 VGPRs spill-free.
__global__ __launch_bounds__(BLOCK, 2)
__attribute__((amdgpu_waves_per_eu(2, 2)))
void arm_rk4_kernel(
    const float* __restrict__ g_state, const float* __restrict__ g_action,
    const float* __restrict__ g_M, const float* __restrict__ g_A,
    const float* __restrict__ g_G, const float* __restrict__ g_grav,
    float* __restrict__ g_out_state, float* __restrict__ g_out_ee)
{
  __shared__ float sMR[8][9];
  __shared__ float sMp[8][3];
  __shared__ float sIR[7][9];
  __shared__ float sIp[7][3];
  __shared__ float sA[7][6];
  __shared__ float sG[7][4];
  __shared__ float sg[3];
  __shared__ float sRB[7*18*EP];   // per joint: R[9], B[9]  (AdT = [[R,0],[B,R]])
  __shared__ float sVV[7*12*EP];   // per joint: Vw,Vv,Dw,Dv (bias sweep history)
  __shared__ float tauL[NDOF*EP];
  __shared__ float dqsL[NDOF*EP];
  __shared__ float qaccL[NDOF*EP];
  __shared__ float qfL[NDOF*EP];
  __shared__ float MllL[28*EP];

  const int tid = threadIdx.x;
  const int e = tid >> 3;
  const int r = tid & 7;
  const int base = tid & 0x38;   // lane index of (e, role 0)
  const int b = blockIdx.x * EPB + e;

  if (tid < 8) {
    const float* Mi = g_M + tid*16;
    float a1[3] = {Mi[0], Mi[4], Mi[8]};
    float a2[3] = {Mi[1], Mi[5], Mi[9]};
    float p[3]  = {Mi[3], Mi[7], Mi[11]};
    float n1 = sqrtf(a1[0]*a1[0] + a1[1]*a1[1] + a1[2]*a1[2]);
    float b1[3] = {a1[0]/n1, a1[1]/n1, a1[2]/n1};
    float d = a2[0]*b1[0] + a2[1]*b1[1] + a2[2]*b1[2];
    float a2o[3] = {a2[0]-d*b1[0], a2[1]-d*b1[1], a2[2]-d*b1[2]};
    float n2 = sqrtf(a2o[0]*a2o[0] + a2o[1]*a2o[1] + a2o[2]*a2o[2]);
    float b2[3] = {a2o[0]/n2, a2o[1]/n2, a2o[2]/n2};
    float b3[3];
    cross3(b3, b1, b2);
    float R[9] = {b1[0], b2[0], b3[0],  b1[1], b2[1], b3[1],  b1[2], b2[2], b3[2]};
#pragma unroll
    for (int k = 0; k < 9; k++) sMR[tid][k] = R[k];
    sMp[tid][0] = p[0]; sMp[tid][1] = p[1]; sMp[tid][2] = p[2];
    if (tid < 7) {
#pragma unroll
      for (int rr = 0; rr < 3; rr++)
#pragma unroll
        for (int cc = 0; cc < 3; cc++) sIR[tid][rr*3+cc] = R[cc*3+rr];
#pragma unroll
      for (int rr = 0; rr < 3; rr++)
        sIp[tid][rr] = -(R[0*3+rr]*p[0] + R[1*3+rr]*p[1] + R[2*3+rr]*p[2]);
      const float* Ar = g_A + tid*6;
      float nw = sqrtf(Ar[0]*Ar[0] + Ar[1]*Ar[1] + Ar[2]*Ar[2]);
      sA[tid][0] = Ar[0]/nw; sA[tid][1] = Ar[1]/nw; sA[tid][2] = Ar[2]/nw;
      sA[tid][3] = Ar[3];    sA[tid][4] = Ar[4];    sA[tid][5] = Ar[5];
      sG[tid][0] = fabsf(g_G[tid*4+0]);
      sG[tid][1] = fabsf(g_G[tid*4+1]);
      sG[tid][2] = fabsf(g_G[tid*4+2]);
      sG[tid][3] = fabsf(g_G[tid*4+3]);
    }
  }
  if (tid == 0) { sg[0] = g_grav[0]; sg[1] = g_grav[1]; sg[2] = g_grav[2]; }

  float q0 = 0.f, dq0 = 0.f, qs = 0.f, dqs = 0.f;
  float accq = 0.f, accd = 0.f;
  if (r < NDOF) {
    q0  = g_state[b*14 + r];
    dq0 = g_state[b*14 + 7 + r];
    float tau = g_action[b*7 + r] * ACTION_RANGE;
    qs = q0; dqs = dq0;
    tauL[r*EP + e] = tau;
    dqsL[r*EP + e] = dq0;
  }
  __syncthreads();

#pragma unroll 1
  for (int st = 0; st < 4; st++) {
    float bias_reg[NDOF];   // r==7 lanes: carried B -> D within this stage

    // ---- (A) adjoint of joint r, lanes r<7 ----
    if (r < NDOF) {
      const int i = r;
      float Ai[6];
#pragma unroll
      for (int k = 0; k < 6; k++) Ai[k] = sA[i][k];
      float Re[9], pe[3];
      exp_se3(Ai, -qs, Re, pe);
      float IRl[9];
#pragma unroll
      for (int k = 0; k < 9; k++) IRl[k] = sIR[i][k];
      float Tr9[9];
      mat3_mul(Tr9, Re, IRl);
      float Ipl[3] = {sIp[i][0], sIp[i][1], sIp[i][2]};
      float Tp[3];
      mat3_vec(Tp, Re, Ipl);
      Tp[0] += pe[0]; Tp[1] += pe[1]; Tp[2] += pe[2];
      float Bm[9];
#pragma unroll
      for (int c = 0; c < 3; c++) {
        Bm[0*3+c] = -Tp[2]*Tr9[1*3+c] + Tp[1]*Tr9[2*3+c];
        Bm[1*3+c] =  Tp[2]*Tr9[0*3+c] - Tp[0]*Tr9[2*3+c];
        Bm[2*3+c] = -Tp[1]*Tr9[0*3+c] + Tp[0]*Tr9[1*3+c];
      }
#pragma unroll
      for (int k = 0; k < 9; k++) {
        sRB[(i*18 +     k)*EP + e] = Tr9[k];
        sRB[(i*18 + 9 + k)*EP + e] = Bm[k];
      }
    }
    __syncthreads();

    // ---- (B) bias sweep, lane r==7 (history in LDS) ----
    if (r == NDOF) {
      float Vw[3] = {0,0,0}, Vv[3] = {0,0,0};
      float Dw[3] = {0,0,0}, Dv[3] = {-sg[0], -sg[1], -sg[2]};
#pragma unroll
      for (int i = 0; i < NDOF; i++) {
        float R[9], Bm[9];
#pragma unroll
        for (int k = 0; k < 9; k++) {
          R[k]  = sRB[(i*18 +     k)*EP + e];
          Bm[k] = sRB[(i*18 + 9 + k)*EP + e];
        }
        float tw[3], tv[3], t2[3];
        mat3_vec(tw, R, Vw);
        mat3_vec(tv, Bm, Vw);
        mat3_vec(t2, R, Vv);
        tv[0] += t2[0]; tv[1] += t2[1]; tv[2] += t2[2];
        float Aw[3] = {sA[i][0], sA[i][1], sA[i][2]};
        float Av[3] = {sA[i][3], sA[i][4], sA[i][5]};
        float dqi = dqsL[i*EP + e];
#pragma unroll
        for (int k = 0; k < 3; k++) { Vw[k] = tw[k] + Aw[k]*dqi; Vv[k] = tv[k] + Av[k]*dqi; }
        mat3_vec(tw, R, Dw);
        mat3_vec(tv, Bm, Dw);
        mat3_vec(t2, R, Dv);
        tv[0] += t2[0]; tv[1] += t2[1]; tv[2] += t2[2];
        float c1[3], c2[3], c3[3];
        cross3(c1, Vw, Aw);
        cross3(c2, Vv, Aw);
        cross3(c3, Vw, Av);
#pragma unroll
        for (int k = 0; k < 3; k++) { Dw[k] = tw[k] + c1[k]*dqi; Dv[k] = tv[k] + (c2[k]+c3[k])*dqi; }
#pragma unroll
        for (int k = 0; k < 3; k++) {
          sVV[(i*12 +     k)*EP + e] = Vw[k];
          sVV[(i*12 + 3 + k)*EP + e] = Vv[k];
          sVV[(i*12 + 6 + k)*EP + e] = Dw[k];
          sVV[(i*12 + 9 + k)*EP + e] = Dv[k];
        }
      }
      float Fw[3] = {0,0,0}, Fv[3] = {0,0,0};
#pragma unroll
      for (int ii = NDOF-1; ii >= 0; ii--) {
        if (ii < NDOF-1) {
          const int j = ii + 1;
          float R[9], Bm[9];
#pragma unroll
          for (int k = 0; k < 9; k++) {
            R[k]  = sRB[(j*18 +     k)*EP + e];
            Bm[k] = sRB[(j*18 + 9 + k)*EP + e];
          }
          float nw[3], nv[3], t[3];
          mat3T_vec(nw, R, Fw);
          mat3T_vec(t, Bm, Fv);
          nw[0] += t[0]; nw[1] += t[1]; nw[2] += t[2];
          mat3T_vec(nv, R, Fv);
          Fw[0] = nw[0]; Fw[1] = nw[1]; Fw[2] = nw[2];
          Fv[0] = nv[0]; Fv[1] = nv[1]; Fv[2] = nv[2];
        }
        float Vwl[3], Vvl[3], Dwl[3], Dvl[3];
#pragma unroll
        for (int k = 0; k < 3; k++) {
          Vwl[k] = sVV[(ii*12 +     k)*EP + e];
          Vvl[k] = sVV[(ii*12 + 3 + k)*EP + e];
          Dwl[k] = sVV[(ii*12 + 6 + k)*EP + e];
          Dvl[k] = sVV[(ii*12 + 9 + k)*EP + e];
        }
        float gx = sG[ii][0], gy = sG[ii][1], gz = sG[ii][2], m = sG[ii][3];
        float GVw[3] = {gx*Vwl[0], gy*Vwl[1], gz*Vwl[2]};
        float GVv[3] = {m*Vvl[0],  m*Vvl[1],  m*Vvl[2]};
        float GDw[3] = {gx*Dwl[0], gy*Dwl[1], gz*Dwl[2]};
        float GDv[3] = {m*Dvl[0],  m*Dvl[1],  m*Dvl[2]};
        float c1[3], c2[3], c3[3];
        cross3(c1, Vwl, GVw);
        cross3(c2, Vvl, GVv);
        cross3(c3, Vwl, GVv);
#pragma unroll
        for (int k = 0; k < 3; k++) { Fw[k] += GDw[k] + c1[k] + c2[k]; Fv[k] += GDv[k] + c3[k]; }
        bias_reg[ii] = Fw[0]*sA[ii][0] + Fw[1]*sA[ii][1] + Fw[2]*sA[ii][2]
                     + Fv[0]*sA[ii][3] + Fv[1]*sA[ii][4] + Fv[2]*sA[ii][5];
      }
    }

    // ---- (C) mass matrix, direct sum, ALL 64 lanes (uniform, no history) ----
    // Lane (e, j): X = X_{k,j} (current only). M_ij = sum_k X_ki . (G_k X_kj),
    // X_ki fetched cross-lane via __shfl. X stays exactly 0 for k<j, so i>k
    // terms vanish -> triangular inner unroll.
    {
      float Xw[3] = {0.f, 0.f, 0.f}, Xv[3] = {0.f, 0.f, 0.f};
      float Macc[NDOF] = {0.f, 0.f, 0.f, 0.f, 0.f, 0.f, 0.f};
#pragma unroll
      for (int k = 0; k < NDOF; k++) {
        float R[9], Bm[9];
#pragma unroll
        for (int kk = 0; kk < 9; kk++) {
          R[kk]  = sRB[(k*18 +      kk)*EP + e];
          Bm[kk] = sRB[(k*18 +  9 + kk)*EP + e];
        }
        float tw[3], tv[3], t2[3];
        mat3_vec(tw, R,  Xw);
        mat3_vec(tv, Bm, Xw);
        mat3_vec(t2, R,  Xv);
        const bool mine = (k == r);
#pragma unroll
        for (int c = 0; c < 3; c++) {
          Xw[c] = mine ? sA[k][c]     : tw[c];
          Xv[c] = mine ? sA[k][3 + c] : (tv[c] + t2[c]);
        }
        float Yw[3] = {sG[k][0]*Xw[0], sG[k][1]*Xw[1], sG[k][2]*Xw[2]};
        float Yv[3] = {sG[k][3]*Xv[0], sG[k][3]*Xv[1], sG[k][3]*Xv[2]};
#pragma unroll
        for (int i = 0; i <= k; i++) {
          float xw0 = __shfl(Xw[0], base + i, 64);
          float xw1 = __shfl(Xw[1], base + i, 64);
          float xw2 = __shfl(Xw[2], base + i, 64);
          float xv0 = __shfl(Xv[0], base + i, 64);
          float xv1 = __shfl(Xv[1], base + i, 64);
          float xv2 = __shfl(Xv[2], base + i, 64);
          Macc[i] += xw0*Yw[0] + xw1*Yw[1] + xw2*Yw[2]
                   + xv0*Yv[0] + xv1*Yv[1] + xv2*Yv[2];
        }
      }
      if (r < NDOF) {
#pragma unroll
        for (int i = 0; i < NDOF; i++)
          if (i >= r) MllL[(i*(i+1)/2 + r)*EP + e] = Macc[i];
      }
    }
    __syncthreads();

    // ---- (D) Cholesky solve, lane r==7 ----
    if (r == NDOF) {
      float Lm[28];
#pragma unroll
      for (int idx = 0; idx < 28; idx++) Lm[idx] = MllL[idx*EP + e];
      float y[NDOF];
#pragma unroll
      for (int i = 0; i < NDOF; i++) y[i] = tauL[i*EP + e] - bias_reg[i];
#pragma unroll
      for (int k = 0; k < NDOF; k++) {
        float d = Lm[k*(k+1)/2 + k];
#pragma unroll
        for (int m2 = 0; m2 < k; m2++) { float l = Lm[k*(k+1)/2 + m2]; d -= l*l; }
        d = sqrtf(d);
        Lm[k*(k+1)/2 + k] = d;
        float inv = 1.0f / d;
#pragma unroll
        for (int i = k+1; i < NDOF; i++) {
          float s = Lm[i*(i+1)/2 + k];
#pragma unroll
          for (int m2 = 0; m2 < k; m2++) s -= Lm[i*(i+1)/2 + m2]*Lm[k*(k+1)/2 + m2];
          Lm[i*(i+1)/2 + k] = s * inv;
        }
      }
#pragma unroll
      for (int i = 0; i < NDOF; i++) {
        float s = y[i];
#pragma unroll
        for (int m2 = 0; m2 < i; m2++) s -= Lm[i*(i+1)/2 + m2]*y[m2];
        y[i] = s / Lm[i*(i+1)/2 + i];
      }
      float qac[NDOF];
#pragma unroll
      for (int i = NDOF-1; i >= 0; i--) {
        float s = y[i];
#pragma unroll
        for (int m2 = i+1; m2 < NDOF; m2++) s -= Lm[m2*(m2+1)/2 + i]*qac[m2];
        qac[i] = s / Lm[i*(i+1)/2 + i];
      }
#pragma unroll
      for (int i = 0; i < NDOF; i++) qaccL[i*EP + e] = qac[i];
    }
    __syncthreads();

    // ---- (E) RK4 stage update, lanes r<7 ----
    if (r < NDOF) {
      float a = qaccL[r*EP + e];
      float w = (st == 0 || st == 3) ? 1.0f : 2.0f;
      accq += w * dqs;
      accd += w * a;
      if (st < 3) {
        float c = (st == 2) ? HSTEP : 0.5f*HSTEP;
        qs  = q0  + c * dqs;
        dqs = dq0 + c * a;
        dqsL[r*EP + e] = dqs;
      }
    }
    // next stage's post-(A) barrier orders dqsL (E write -> B read) and
    // qaccL (E read -> next D write); MllL WAR covered by post-(C) barrier.
  }

  const float h6 = HSTEP / 6.0f;
  if (r < NDOF) {
    float qf = wrap_pi(q0 + h6*accq);
    float v  = dq0 + h6*accd;
    float dqf = fminf(fmaxf(v, -MAX_VEL), MAX_VEL);
    qfL[r*EP + e] = qf;
    g_out_state[b*14 + r]     = qf;
    g_out_state[b*14 + 7 + r] = dqf;
  }
  __syncthreads();

  if (r == NDOF) {
    float Tr9[9] = {1,0,0, 0,1,0, 0,0,1};
    float Tp[3] = {0,0,0};
#pragma unroll
    for (int i = 0; i < NDOF; i++) {
      float MRl[9];
#pragma unroll
      for (int k = 0; k < 9; k++) MRl[k] = sMR[i][k];
      float Mpl[3] = {sMp[i][0], sMp[i][1], sMp[i][2]};
      float R1[9];
      mat3_mul(R1, Tr9, MRl);
      float p1[3];
      mat3_vec(p1, Tr9, Mpl);
      p1[0] += Tp[0]; p1[1] += Tp[1]; p1[2] += Tp[2];
      float Ai[6];
#pragma unroll
      for (int k = 0; k < 6; k++) Ai[k] = sA[i][k];
      float Re[9], pe[3];
      exp_se3(Ai, qfL[i*EP + e], Re, pe);
      mat3_mul(Tr9, R1, Re);
      mat3_vec(Tp, R1, pe);
      Tp[0] += p1[0]; Tp[1] += p1[1]; Tp[2] += p1[2];
    }
    float Mp7[3] = {sMp[7][0], sMp[7][1], sMp[7][2]};
    float pf[3];
    mat3_vec(pf, Tr9, Mp7);
    g_out_ee[b*2 + 0] = pf[0] + Tp[0];
    g_out_ee[b*2 + 1] = pf[1] + Tp[1];
  }
}

extern "C" void kernel_launch(void* const* d_in, const int* in_sizes, int n_in,
                              void* d_out, int out_size, void* d_ws, size_t ws_size,
                              hipStream_t stream) {
  const float* state  = (const float*)d_in[0];  // (16384,14)
  const float* action = (const float*)d_in[1];  // (16384,7)
  const float* M      = (const float*)d_in[2];  // (8,4,4)
  const float* A      = (const float*)d_in[3];  // (7,6)
  const float* G      = (const float*)d_in[4];  // (7,4)
  const float* grav   = (const float*)d_in[5];  // (3,)
  float* out_state = (float*)d_out;                       // (16384,14)
  float* out_ee    = (float*)d_out + (size_t)BATCH * 14;  // (16384,2)

  arm_rk4_kernel<<<BATCH / EPB, BLOCK, 0, stream>>>(
      state, action, M, A, G, grav, out_state, out_ee);
}

// Round 7
// 151.151 us; speedup vs baseline: 1.0593x; 1.0593x over previous
//
#include <hip/hip_runtime.h>
#include <math.h>

#define BLOCK 64
#define BATCH 16384
#define EPB 8      // elements per block (one wave = 8 elements x 8 roles)
#define EP 11      // element-dim stride (8 elems + pad) for per-element LDS
#define NDOF 7
#define ACTION_RANGE 50.0f
#define MAX_VEL 20.0f
#define HSTEP 0.1f

__device__ __forceinline__ void mat3_mul(float* C, const float* A, const float* B) {
#pragma unroll
  for (int r = 0; r < 3; r++) {
#pragma unroll
    for (int c = 0; c < 3; c++) {
      C[r*3+c] = A[r*3+0]*B[0*3+c] + A[r*3+1]*B[1*3+c] + A[r*3+2]*B[2*3+c];
    }
  }
}

__device__ __forceinline__ void mat3_vec(float* y, const float* A, const float* x) {
#pragma unroll
  for (int r = 0; r < 3; r++)
    y[r] = A[r*3+0]*x[0] + A[r*3+1]*x[1] + A[r*3+2]*x[2];
}

__device__ __forceinline__ void mat3T_vec(float* y, const float* A, const float* x) {
#pragma unroll
  for (int r = 0; r < 3; r++)
    y[r] = A[0*3+r]*x[0] + A[1*3+r]*x[1] + A[2*3+r]*x[2];
}

__device__ __forceinline__ void cross3(float* y, const float* a, const float* b) {
  y[0] = a[1]*b[2] - a[2]*b[1];
  y[1] = a[2]*b[0] - a[0]*b[2];
  y[2] = a[0]*b[1] - a[1]*b[0];
}

// R = I + s*W + (1-c)*W^2 ; p = (th*I + (1-c)*W + (th-s)*W^2) v
// R7: __sinf/__cosf (inline v_sin_f32/v_cos_f32) instead of sincosf.
// sincosf -> __ocml_sincos_f32(float, float*) is a real CALL with a stack
// frame + Payne-Hanek tables; its per-call scratch traffic (~100-270 B/call,
// write-heavy) matches R2..R6's unexplained 50-210 MB/dispatch HBM traffic.
// |th| <~ 8 rad here, so hw sin/cos accuracy is far inside the threshold.
__device__ __forceinline__ void exp_se3(const float* A6, float th, float* R, float* p) {
  float w0 = A6[0], w1 = A6[1], w2 = A6[2];
  float s = __sinf(th);
  float c = __cosf(th);
  float omc = 1.0f - c, tms = th - s;
  float W[9]  = {0.f, -w2, w1,  w2, 0.f, -w0,  -w1, w0, 0.f};
  float W2[9];
  mat3_mul(W2, W, W);
#pragma unroll
  for (int k = 0; k < 9; k++) R[k] = s*W[k] + omc*W2[k];
  R[0] += 1.f; R[4] += 1.f; R[8] += 1.f;
  float G[9];
#pragma unroll
  for (int k = 0; k < 9; k++) G[k] = omc*W[k] + tms*W2[k];
  G[0] += th; G[4] += th; G[8] += th;
  mat3_vec(p, G, A6 + 3);
}

// python-style mod: a - floor(a/y)*y  (result in [0,y))
__device__ __forceinline__ float wrap_pi(float x) {
  const float PI_F   = 3.14159265358979323846f;
  const float TWO_PI = 6.28318530717958647692f;
  float a = x + PI_F;
  float r = a - floorf(a * (1.0f / TWO_PI)) * TWO_PI;
  return r - PI_F;
}

// 8 lanes per element: role r = lane&7, element slot e = lane>>3.
// Structure = R5 (best so far: 91 us); only exp_se3's sin/cos changed.
__global__ __launch_bounds__(BLOCK, 2) void arm_rk4_kernel(
    const float* __restrict__ g_state, const float* __restrict__ g_action,
    const float* __restrict__ g_M, const float* __restrict__ g_A,
    const float* __restrict__ g_G, const float* __restrict__ g_grav,
    float* __restrict__ g_out_state, float* __restrict__ g_out_ee)
{
  __shared__ float sMR[8][9];
  __shared__ float sMp[8][3];
  __shared__ float sIR[7][9];
  __shared__ float sIp[7][3];
  __shared__ float sA[7][6];
  __shared__ float sG[7][4];
  __shared__ float sg[3];
  __shared__ float sRB[7*18*EP];   // per joint: R[9], B[9]  (AdT = [[R,0],[B,R]])
  __shared__ float sVV[7*12*EP];   // per joint: Vw,Vv,Dw,Dv (bias sweep history)
  __shared__ float tauL[NDOF*EP];
  __shared__ float dqsL[NDOF*EP];
  __shared__ float qaccL[NDOF*EP];
  __shared__ float qfL[NDOF*EP];
  __shared__ float MllL[28*EP];

  const int tid = threadIdx.x;
  const int e = tid >> 3;
  const int r = tid & 7;
  const int b = blockIdx.x * EPB + e;

  if (tid < 8) {
    const float* Mi = g_M + tid*16;
    float a1[3] = {Mi[0], Mi[4], Mi[8]};
    float a2[3] = {Mi[1], Mi[5], Mi[9]};
    float p[3]  = {Mi[3], Mi[7], Mi[11]};
    float n1 = sqrtf(a1[0]*a1[0] + a1[1]*a1[1] + a1[2]*a1[2]);
    float b1[3] = {a1[0]/n1, a1[1]/n1, a1[2]/n1};
    float d = a2[0]*b1[0] + a2[1]*b1[1] + a2[2]*b1[2];
    float a2o[3] = {a2[0]-d*b1[0], a2[1]-d*b1[1], a2[2]-d*b1[2]};
    float n2 = sqrtf(a2o[0]*a2o[0] + a2o[1]*a2o[1] + a2o[2]*a2o[2]);
    float b2[3] = {a2o[0]/n2, a2o[1]/n2, a2o[2]/n2};
    float b3[3];
    cross3(b3, b1, b2);
    float R[9] = {b1[0], b2[0], b3[0],  b1[1], b2[1], b3[1],  b1[2], b2[2], b3[2]};
#pragma unroll
    for (int k = 0; k < 9; k++) sMR[tid][k] = R[k];
    sMp[tid][0] = p[0]; sMp[tid][1] = p[1]; sMp[tid][2] = p[2];
    if (tid < 7) {
#pragma unroll
      for (int rr = 0; rr < 3; rr++)
#pragma unroll
        for (int cc = 0; cc < 3; cc++) sIR[tid][rr*3+cc] = R[cc*3+rr];
#pragma unroll
      for (int rr = 0; rr < 3; rr++)
        sIp[tid][rr] = -(R[0*3+rr]*p[0] + R[1*3+rr]*p[1] + R[2*3+rr]*p[2]);
      const float* Ar = g_A + tid*6;
      float nw = sqrtf(Ar[0]*Ar[0] + Ar[1]*Ar[1] + Ar[2]*Ar[2]);
      sA[tid][0] = Ar[0]/nw; sA[tid][1] = Ar[1]/nw; sA[tid][2] = Ar[2]/nw;
      sA[tid][3] = Ar[3];    sA[tid][4] = Ar[4];    sA[tid][5] = Ar[5];
      sG[tid][0] = fabsf(g_G[tid*4+0]);
      sG[tid][1] = fabsf(g_G[tid*4+1]);
      sG[tid][2] = fabsf(g_G[tid*4+2]);
      sG[tid][3] = fabsf(g_G[tid*4+3]);
    }
  }
  if (tid == 0) { sg[0] = g_grav[0]; sg[1] = g_grav[1]; sg[2] = g_grav[2]; }

  float q0 = 0.f, dq0 = 0.f, qs = 0.f, dqs = 0.f;
  float accq = 0.f, accd = 0.f;
  if (r < NDOF) {
    q0  = g_state[b*14 + r];
    dq0 = g_state[b*14 + 7 + r];
    float tau = g_action[b*7 + r] * ACTION_RANGE;
    qs = q0; dqs = dq0;
    tauL[r*EP + e] = tau;
    dqsL[r*EP + e] = dq0;
  }
  __syncthreads();

#pragma unroll 1
  for (int st = 0; st < 4; st++) {
    float bias_reg[NDOF];   // r==7 lanes: carried B -> D within this stage

    // ---- (A) adjoint of joint r, lanes r<7 ----
    if (r < NDOF) {
      const int i = r;
      float Ai[6];
#pragma unroll
      for (int k = 0; k < 6; k++) Ai[k] = sA[i][k];
      float Re[9], pe[3];
      exp_se3(Ai, -qs, Re, pe);
      float IRl[9];
#pragma unroll
      for (int k = 0; k < 9; k++) IRl[k] = sIR[i][k];
      float Tr9[9];
      mat3_mul(Tr9, Re, IRl);
      float Ipl[3] = {sIp[i][0], sIp[i][1], sIp[i][2]};
      float Tp[3];
      mat3_vec(Tp, Re, Ipl);
      Tp[0] += pe[0]; Tp[1] += pe[1]; Tp[2] += pe[2];
      float Bm[9];
#pragma unroll
      for (int c = 0; c < 3; c++) {
        Bm[0*3+c] = -Tp[2]*Tr9[1*3+c] + Tp[1]*Tr9[2*3+c];
        Bm[1*3+c] =  Tp[2]*Tr9[0*3+c] - Tp[0]*Tr9[2*3+c];
        Bm[2*3+c] = -Tp[1]*Tr9[0*3+c] + Tp[0]*Tr9[1*3+c];
      }
#pragma unroll
      for (int k = 0; k < 9; k++) {
        sRB[(i*18 +     k)*EP + e] = Tr9[k];
        sRB[(i*18 + 9 + k)*EP + e] = Bm[k];
      }
    }
    __syncthreads();

    // ---- (B) bias sweep, lane r==7 (history in LDS) ----
    if (r == NDOF) {
      float Vw[3] = {0,0,0}, Vv[3] = {0,0,0};
      float Dw[3] = {0,0,0}, Dv[3] = {-sg[0], -sg[1], -sg[2]};
#pragma unroll
      for (int i = 0; i < NDOF; i++) {
        float R[9], Bm[9];
#pragma unroll
        for (int k = 0; k < 9; k++) {
          R[k]  = sRB[(i*18 +     k)*EP + e];
          Bm[k] = sRB[(i*18 + 9 + k)*EP + e];
        }
        float tw[3], tv[3], t2[3];
        mat3_vec(tw, R, Vw);
        mat3_vec(tv, Bm, Vw);
        mat3_vec(t2, R, Vv);
        tv[0] += t2[0]; tv[1] += t2[1]; tv[2] += t2[2];
        float Aw[3] = {sA[i][0], sA[i][1], sA[i][2]};
        float Av[3] = {sA[i][3], sA[i][4], sA[i][5]};
        float dqi = dqsL[i*EP + e];
#pragma unroll
        for (int k = 0; k < 3; k++) { Vw[k] = tw[k] + Aw[k]*dqi; Vv[k] = tv[k] + Av[k]*dqi; }
        mat3_vec(tw, R, Dw);
        mat3_vec(tv, Bm, Dw);
        mat3_vec(t2, R, Dv);
        tv[0] += t2[0]; tv[1] += t2[1]; tv[2] += t2[2];
        float c1[3], c2[3], c3[3];
        cross3(c1, Vw, Aw);
        cross3(c2, Vv, Aw);
        cross3(c3, Vw, Av);
#pragma unroll
        for (int k = 0; k < 3; k++) { Dw[k] = tw[k] + c1[k]*dqi; Dv[k] = tv[k] + (c2[k]+c3[k])*dqi; }
#pragma unroll
        for (int k = 0; k < 3; k++) {
          sVV[(i*12 +     k)*EP + e] = Vw[k];
          sVV[(i*12 + 3 + k)*EP + e] = Vv[k];
          sVV[(i*12 + 6 + k)*EP + e] = Dw[k];
          sVV[(i*12 + 9 + k)*EP + e] = Dv[k];
        }
      }
      float Fw[3] = {0,0,0}, Fv[3] = {0,0,0};
#pragma unroll
      for (int ii = NDOF-1; ii >= 0; ii--) {
        if (ii < NDOF-1) {
          const int j = ii + 1;
          float R[9], Bm[9];
#pragma unroll
          for (int k = 0; k < 9; k++) {
            R[k]  = sRB[(j*18 +     k)*EP + e];
            Bm[k] = sRB[(j*18 + 9 + k)*EP + e];
          }
          float nw[3], nv[3], t[3];
          mat3T_vec(nw, R, Fw);
          mat3T_vec(t, Bm, Fv);
          nw[0] += t[0]; nw[1] += t[1]; nw[2] += t[2];
          mat3T_vec(nv, R, Fv);
          Fw[0] = nw[0]; Fw[1] = nw[1]; Fw[2] = nw[2];
          Fv[0] = nv[0]; Fv[1] = nv[1]; Fv[2] = nv[2];
        }
        float Vwl[3], Vvl[3], Dwl[3], Dvl[3];
#pragma unroll
        for (int k = 0; k < 3; k++) {
          Vwl[k] = sVV[(ii*12 +     k)*EP + e];
          Vvl[k] = sVV[(ii*12 + 3 + k)*EP + e];
          Dwl[k] = sVV[(ii*12 + 6 + k)*EP + e];
          Dvl[k] = sVV[(ii*12 + 9 + k)*EP + e];
        }
        float gx = sG[ii][0], gy = sG[ii][1], gz = sG[ii][2], m = sG[ii][3];
        float GVw[3] = {gx*Vwl[0], gy*Vwl[1], gz*Vwl[2]};
        float GVv[3] = {m*Vvl[0],  m*Vvl[1],  m*Vvl[2]};
        float GDw[3] = {gx*Dwl[0], gy*Dwl[1], gz*Dwl[2]};
        float GDv[3] = {m*Dvl[0],  m*Dvl[1],  m*Dvl[2]};
        float c1[3], c2[3], c3[3];
        cross3(c1, Vwl, GVw);
        cross3(c2, Vvl, GVv);
        cross3(c3, Vwl, GVv);
#pragma unroll
        for (int k = 0; k < 3; k++) { Fw[k] += GDw[k] + c1[k] + c2[k]; Fv[k] += GDv[k] + c3[k]; }
        bias_reg[ii] = Fw[0]*sA[ii][0] + Fw[1]*sA[ii][1] + Fw[2]*sA[ii][2]
                     + Fv[0]*sA[ii][3] + Fv[1]*sA[ii][4] + Fv[2]*sA[ii][5];
      }
    }

    // ---- (C) mass-matrix column r, lanes r<7 ----
    if (r < NDOF) {
      float Ajw[3] = {sA[r][0], sA[r][1], sA[r][2]};
      float Ajv[3] = {sA[r][3], sA[r][4], sA[r][5]};
      float Xw[NDOF][3], Xv[NDOF][3];
#pragma unroll
      for (int k = 0; k < 3; k++) {
        Xw[0][k] = (r == 0) ? Ajw[k] : 0.f;
        Xv[0][k] = (r == 0) ? Ajv[k] : 0.f;
      }
#pragma unroll
      for (int i = 1; i < NDOF; i++) {
        float R[9], Bm[9];
#pragma unroll
        for (int k = 0; k < 9; k++) {
          R[k]  = sRB[(i*18 +     k)*EP + e];
          Bm[k] = sRB[(i*18 + 9 + k)*EP + e];
        }
        float tw[3], tv[3], t2[3];
        mat3_vec(tw, R,  Xw[i-1]);
        mat3_vec(tv, Bm, Xw[i-1]);
        mat3_vec(t2, R,  Xv[i-1]);
#pragma unroll
        for (int k = 0; k < 3; k++) {
          float w_ = tw[k];
          float v_ = tv[k] + t2[k];
          Xw[i][k] = (i == r) ? Ajw[k] : w_;
          Xv[i][k] = (i == r) ? Ajv[k] : v_;
        }
      }
      float Fw[3] = {0,0,0}, Fv[3] = {0,0,0};
#pragma unroll
      for (int i = NDOF-1; i >= 0; i--) {
        if (i < NDOF-1) {
          const int jn = i + 1;
          float R[9], Bm[9];
#pragma unroll
          for (int k = 0; k < 9; k++) {
            R[k]  = sRB[(jn*18 +     k)*EP + e];
            Bm[k] = sRB[(jn*18 + 9 + k)*EP + e];
          }
          float nw[3], nv[3], t[3];
          mat3T_vec(nw, R, Fw);
          mat3T_vec(t, Bm, Fv);
          nw[0] += t[0]; nw[1] += t[1]; nw[2] += t[2];
          mat3T_vec(nv, R, Fv);
          Fw[0] = nw[0]; Fw[1] = nw[1]; Fw[2] = nw[2];
          Fv[0] = nv[0]; Fv[1] = nv[1]; Fv[2] = nv[2];
        }
        Fw[0] += sG[i][0]*Xw[i][0]; Fw[1] += sG[i][1]*Xw[i][1]; Fw[2] += sG[i][2]*Xw[i][2];
        Fv[0] += sG[i][3]*Xv[i][0]; Fv[1] += sG[i][3]*Xv[i][1]; Fv[2] += sG[i][3]*Xv[i][2];
        float Mij = Fw[0]*sA[i][0] + Fw[1]*sA[i][1] + Fw[2]*sA[i][2]
                  + Fv[0]*sA[i][3] + Fv[1]*sA[i][4] + Fv[2]*sA[i][5];
        if (i >= r) MllL[(i*(i+1)/2 + r)*EP + e] = Mij;
      }
    }
    __syncthreads();

    // ---- (D) Cholesky solve, lane r==7 ----
    if (r == NDOF) {
      float Lm[28];
#pragma unroll
      for (int idx = 0; idx < 28; idx++) Lm[idx] = MllL[idx*EP + e];
      float y[NDOF];
#pragma unroll
      for (int i = 0; i < NDOF; i++) y[i] = tauL[i*EP + e] - bias_reg[i];
#pragma unroll
      for (int k = 0; k < NDOF; k++) {
        float d = Lm[k*(k+1)/2 + k];
#pragma unroll
        for (int m2 = 0; m2 < k; m2++) { float l = Lm[k*(k+1)/2 + m2]; d -= l*l; }
        d = sqrtf(d);
        Lm[k*(k+1)/2 + k] = d;
        float inv = 1.0f / d;
#pragma unroll
        for (int i = k+1; i < NDOF; i++) {
          float s = Lm[i*(i+1)/2 + k];
#pragma unroll
          for (int m2 = 0; m2 < k; m2++) s -= Lm[i*(i+1)/2 + m2]*Lm[k*(k+1)/2 + m2];
          Lm[i*(i+1)/2 + k] = s * inv;
        }
      }
#pragma unroll
      for (int i = 0; i < NDOF; i++) {
        float s = y[i];
#pragma unroll
        for (int m2 = 0; m2 < i; m2++) s -= Lm[i*(i+1)/2 + m2]*y[m2];
        y[i] = s / Lm[i*(i+1)/2 + i];
      }
      float qac[NDOF];
#pragma unroll
      for (int i = NDOF-1; i >= 0; i--) {
        float s = y[i];
#pragma unroll
        for (int m2 = i+1; m2 < NDOF; m2++) s -= Lm[m2*(m2+1)/2 + i]*qac[m2];
        qac[i] = s / Lm[i*(i+1)/2 + i];
      }
#pragma unroll
      for (int i = 0; i < NDOF; i++) qaccL[i*EP + e] = qac[i];
    }
    __syncthreads();

    // ---- (E) RK4 stage update, lanes r<7 ----
    if (r < NDOF) {
      float a = qaccL[r*EP + e];
      float w = (st == 0 || st == 3) ? 1.0f : 2.0f;
      accq += w * dqs;
      accd += w * a;
      if (st < 3) {
        float c = (st == 2) ? HSTEP : 0.5f*HSTEP;
        qs  = q0  + c * dqs;
        dqs = dq0 + c * a;
        dqsL[r*EP + e] = dqs;
      }
    }
    // next stage's post-(A) barrier orders dqsL (E write -> B read) and
    // qaccL (E read -> next D write); sRB/sVV WAR covered by post-(C) barrier.
  }

  const float h6 = HSTEP / 6.0f;
  if (r < NDOF) {
    float qf = wrap_pi(q0 + h6*accq);
    float v  = dq0 + h6*accd;
    float dqf = fminf(fmaxf(v, -MAX_VEL), MAX_VEL);
    qfL[r*EP + e] = qf;
    g_out_state[b*14 + r]     = qf;
    g_out_state[b*14 + 7 + r] = dqf;
  }
  __syncthreads();

  if (r == NDOF) {
    float Tr9[9] = {1,0,0, 0,1,0, 0,0,1};
    float Tp[3] = {0,0,0};
#pragma unroll
    for (int i = 0; i < NDOF; i++) {
      float MRl[9];
#pragma unroll
      for (int k = 0; k < 9; k++) MRl[k] = sMR[i][k];
      float Mpl[3] = {sMp[i][0], sMp[i][1], sMp[i][2]};
      float R1[9];
      mat3_mul(R1, Tr9, MRl);
      float p1[3];
      mat3_vec(p1, Tr9, Mpl);
      p1[0] += Tp[0]; p1[1] += Tp[1]; p1[2] += Tp[2];
      float Ai[6];
#pragma unroll
      for (int k = 0; k < 6; k++) Ai[k] = sA[i][k];
      float Re[9], pe[3];
      exp_se3(Ai, qfL[i*EP + e], Re, pe);
      mat3_mul(Tr9, R1, Re);
      mat3_vec(Tp, R1, pe);
      Tp[0] += p1[0]; Tp[1] += p1[1]; Tp[2] += p1[2];
    }
    float Mp7[3] = {sMp[7][0], sMp[7][1], sMp[7][2]};
    float pf[3];
    mat3_vec(pf, Tr9, Mp7);
    g_out_ee[b*2 + 0] = pf[0] + Tp[0];
    g_out_ee[b*2 + 1] = pf[1] + Tp[1];
  }
}

extern "C" void kernel_launch(void* const* d_in, const int* in_sizes, int n_in,
                              void* d_out, int out_size, void* d_ws, size_t ws_size,
                              hipStream_t stream) {
  const float* state  = (const float*)d_in[0];  // (16384,14)
  const float* action = (const float*)d_in[1];  // (16384,7)
  const float* M      = (const float*)d_in[2];  // (8,4,4)
  const float* A      = (const float*)d_in[3];  // (7,6)
  const float* G      = (const float*)d_in[4];  // (7,4)
  const float* grav   = (const float*)d_in[5];  // (3,)
  float* out_state = (float*)d_out;                       // (16384,14)
  float* out_ee    = (float*)d_out + (size_t)BATCH * 14;  // (16384,2)

  arm_rk4_kernel<<<BATCH / EPB, BLOCK, 0, stream>>>(
      state, action, M, A, G, grav, out_state, out_ee);
}

// Round 8
// 137.285 us; speedup vs baseline: 1.1663x; 1.1010x over previous
//
#include <hip/hip_runtime.h>
#include <math.h>

#define BLOCK 64
#define BATCH 16384
#define EPB 4      // elements per block: 16 lanes per element
#define EP 5       // element-dim stride (4 elems + pad) for per-element LDS
#define NDOF 7
#define ACTION_RANGE 50.0f
#define MAX_VEL 20.0f
#define HSTEP 0.1f

__device__ __forceinline__ void mat3_mul(float* C, const float* A, const float* B) {
#pragma unroll
  for (int r = 0; r < 3; r++) {
#pragma unroll
    for (int c = 0; c < 3; c++) {
      C[r*3+c] = A[r*3+0]*B[0*3+c] + A[r*3+1]*B[1*3+c] + A[r*3+2]*B[2*3+c];
    }
  }
}

__device__ __forceinline__ void mat3_vec(float* y, const float* A, const float* x) {
#pragma unroll
  for (int r = 0; r < 3; r++)
    y[r] = A[r*3+0]*x[0] + A[r*3+1]*x[1] + A[r*3+2]*x[2];
}

__device__ __forceinline__ void mat3T_vec(float* y, const float* A, const float* x) {
#pragma unroll
  for (int r = 0; r < 3; r++)
    y[r] = A[0*3+r]*x[0] + A[1*3+r]*x[1] + A[2*3+r]*x[2];
}

__device__ __forceinline__ void cross3(float* y, const float* a, const float* b) {
  y[0] = a[1]*b[2] - a[2]*b[1];
  y[1] = a[2]*b[0] - a[0]*b[2];
  y[2] = a[0]*b[1] - a[1]*b[0];
}

// R = I + s*W + (1-c)*W^2 ; p = (th*I + (1-c)*W + (th-s)*W^2) v
__device__ __forceinline__ void exp_se3(const float* A6, float th, float* R, float* p) {
  float w0 = A6[0], w1 = A6[1], w2 = A6[2];
  float s = __sinf(th);
  float c = __cosf(th);
  float omc = 1.0f - c, tms = th - s;
  float W[9]  = {0.f, -w2, w1,  w2, 0.f, -w0,  -w1, w0, 0.f};
  float W2[9];
  mat3_mul(W2, W, W);
#pragma unroll
  for (int k = 0; k < 9; k++) R[k] = s*W[k] + omc*W2[k];
  R[0] += 1.f; R[4] += 1.f; R[8] += 1.f;
  float G[9];
#pragma unroll
  for (int k = 0; k < 9; k++) G[k] = omc*W[k] + tms*W2[k];
  G[0] += th; G[4] += th; G[8] += th;
  mat3_vec(p, G, A6 + 3);
}

// python-style mod: a - floor(a/y)*y  (result in [0,y))
__device__ __forceinline__ float wrap_pi(float x) {
  const float PI_F   = 3.14159265358979323846f;
  const float TWO_PI = 6.28318530717958647692f;
  float a = x + PI_F;
  float r = a - floorf(a * (1.0f / TWO_PI)) * TWO_PI;
  return r - PI_F;
}

// R8: 16 lanes per element (e = tid>>4, r = tid&15), 4096 blocks = 16 waves/CU.
// The bias computation is FUSED into the mass-matrix sweeps as two extra
// propagated "columns": lane 7 carries V (inject dq_i*A_i each joint), lane 8
// carries Vd (inject dq_i*ad(V)A_i, V shuffled from lane 7). Backward sweep:
// lanes 0-6 accumulate G*X_col (-> M entries), lane 7 accumulates
// G*Vd - ad(V)^T(G V) (-> bias). This deletes the old phase B (~1900
// wave-inst/stage at 1/8-lane utilization) and doubles wave count for latency
// hiding. R4-R7 evidence: HBM traffic is invariant under structural change
// (harness poison writeback in our counting window) -> kernel is
// stream/latency bound, not memory bound.
__global__ __launch_bounds__(BLOCK, 2) void arm_rk4_kernel(
    const float* __restrict__ g_state, const float* __restrict__ g_action,
    const float* __restrict__ g_M, const float* __restrict__ g_A,
    const float* __restrict__ g_G, const float* __restrict__ g_grav,
    float* __restrict__ g_out_state, float* __restrict__ g_out_ee)
{
  __shared__ float sMR[8][9];
  __shared__ float sMp[8][3];
  __shared__ float sIR[7][9];
  __shared__ float sIp[7][3];
  __shared__ float sA[7][6];
  __shared__ float sG[7][4];
  __shared__ float sg[3];
  __shared__ float sRB[7*18*EP];   // per joint: R[9], B[9]  (AdT = [[R,0],[B,R]])
  __shared__ float tauL[NDOF*EP];
  __shared__ float qaccL[NDOF*EP];
  __shared__ float qfL[NDOF*EP];
  __shared__ float MllL[28*EP];

  const int tid  = threadIdx.x;
  const int e    = tid >> 4;      // element slot 0..3
  const int r    = tid & 15;      // role 0..15
  const int base = tid & 0x30;    // first lane of this element group
  const int b    = blockIdx.x * EPB + e;

  if (tid < 8) {
    const float* Mi = g_M + tid*16;
    float a1[3] = {Mi[0], Mi[4], Mi[8]};
    float a2[3] = {Mi[1], Mi[5], Mi[9]};
    float p[3]  = {Mi[3], Mi[7], Mi[11]};
    float n1 = sqrtf(a1[0]*a1[0] + a1[1]*a1[1] + a1[2]*a1[2]);
    float b1[3] = {a1[0]/n1, a1[1]/n1, a1[2]/n1};
    float d = a2[0]*b1[0] + a2[1]*b1[1] + a2[2]*b1[2];
    float a2o[3] = {a2[0]-d*b1[0], a2[1]-d*b1[1], a2[2]-d*b1[2]};
    float n2 = sqrtf(a2o[0]*a2o[0] + a2o[1]*a2o[1] + a2o[2]*a2o[2]);
    float b2[3] = {a2o[0]/n2, a2o[1]/n2, a2o[2]/n2};
    float b3[3];
    cross3(b3, b1, b2);
    float R[9] = {b1[0], b2[0], b3[0],  b1[1], b2[1], b3[1],  b1[2], b2[2], b3[2]};
#pragma unroll
    for (int k = 0; k < 9; k++) sMR[tid][k] = R[k];
    sMp[tid][0] = p[0]; sMp[tid][1] = p[1]; sMp[tid][2] = p[2];
    if (tid < 7) {
#pragma unroll
      for (int rr = 0; rr < 3; rr++)
#pragma unroll
        for (int cc = 0; cc < 3; cc++) sIR[tid][rr*3+cc] = R[cc*3+rr];
#pragma unroll
      for (int rr = 0; rr < 3; rr++)
        sIp[tid][rr] = -(R[0*3+rr]*p[0] + R[1*3+rr]*p[1] + R[2*3+rr]*p[2]);
      const float* Ar = g_A + tid*6;
      float nw = sqrtf(Ar[0]*Ar[0] + Ar[1]*Ar[1] + Ar[2]*Ar[2]);
      sA[tid][0] = Ar[0]/nw; sA[tid][1] = Ar[1]/nw; sA[tid][2] = Ar[2]/nw;
      sA[tid][3] = Ar[3];    sA[tid][4] = Ar[4];    sA[tid][5] = Ar[5];
      sG[tid][0] = fabsf(g_G[tid*4+0]);
      sG[tid][1] = fabsf(g_G[tid*4+1]);
      sG[tid][2] = fabsf(g_G[tid*4+2]);
      sG[tid][3] = fabsf(g_G[tid*4+3]);
    }
  }
  if (tid == 0) { sg[0] = g_grav[0]; sg[1] = g_grav[1]; sg[2] = g_grav[2]; }

  float q0 = 0.f, dq0 = 0.f, qs = 0.f, dqs = 0.f;
  float accq = 0.f, accd = 0.f;
  if (r < NDOF) {
    q0  = g_state[b*14 + r];
    dq0 = g_state[b*14 + 7 + r];
    float tau = g_action[b*7 + r] * ACTION_RANGE;
    qs = q0; dqs = dq0;
    tauL[r*EP + e] = tau;
  }
  __syncthreads();

#pragma unroll 1
  for (int st = 0; st < 4; st++) {
    float bias_reg[NDOF];   // valid on lane r==7 (fused sweep -> D)

    // ---- (A) adjoint of joint r, lanes r<7 ----
    if (r < NDOF) {
      const int i = r;
      float Ai[6];
#pragma unroll
      for (int k = 0; k < 6; k++) Ai[k] = sA[i][k];
      float Re[9], pe[3];
      exp_se3(Ai, -qs, Re, pe);
      float IRl[9];
#pragma unroll
      for (int k = 0; k < 9; k++) IRl[k] = sIR[i][k];
      float Tr9[9];
      mat3_mul(Tr9, Re, IRl);
      float Ipl[3] = {sIp[i][0], sIp[i][1], sIp[i][2]};
      float Tp[3];
      mat3_vec(Tp, Re, Ipl);
      Tp[0] += pe[0]; Tp[1] += pe[1]; Tp[2] += pe[2];
      float Bm[9];
#pragma unroll
      for (int c = 0; c < 3; c++) {
        Bm[0*3+c] = -Tp[2]*Tr9[1*3+c] + Tp[1]*Tr9[2*3+c];
        Bm[1*3+c] =  Tp[2]*Tr9[0*3+c] - Tp[0]*Tr9[2*3+c];
        Bm[2*3+c] = -Tp[1]*Tr9[0*3+c] + Tp[0]*Tr9[1*3+c];
      }
#pragma unroll
      for (int k = 0; k < 9; k++) {
        sRB[(r*18 +     k)*EP + e] = Tr9[k];
        sRB[(r*18 + 9 + k)*EP + e] = Bm[k];
      }
    }
    __syncthreads();

    // ---- (BC) fused forward+backward sweep, ALL lanes ----
    // lane r<7 : P = mass column r (inject A_r at joint r)
    // lane 7   : P = V   (inject dq_i*A_i at every joint)
    // lane 8   : P = Vd  (gravity init; inject dq_i*ad(V)A_i, V from lane 7)
    // lanes 9+ : propagate zeros (harmless)
    {
      float Phw[NDOF][3], Phv[NDOF][3];
      float Pw[3] = {0.f, 0.f, 0.f};
      float Pv[3] = {0.f, 0.f, 0.f};
      if (r == 8) { Pv[0] = -sg[0]; Pv[1] = -sg[1]; Pv[2] = -sg[2]; }
#pragma unroll
      for (int i = 0; i < NDOF; i++) {
        float R[9], Bm[9];
#pragma unroll
        for (int k = 0; k < 9; k++) {
          R[k]  = sRB[(i*18 +     k)*EP + e];
          Bm[k] = sRB[(i*18 + 9 + k)*EP + e];
        }
        float dqi = __shfl(dqs, base + i, 64);
        float Tw[3], Tv[3], t2[3];
        mat3_vec(Tw, R,  Pw);
        mat3_vec(Tv, Bm, Pw);
        mat3_vec(t2, R,  Pv);
        Tv[0] += t2[0]; Tv[1] += t2[1]; Tv[2] += t2[2];
        float Aw[3] = {sA[i][0], sA[i][1], sA[i][2]};
        float Av[3] = {sA[i][3], sA[i][4], sA[i][5]};
        float cA = (r == i) ? 1.f : ((r == 7) ? dqi : 0.f);
#pragma unroll
        for (int k = 0; k < 3; k++) { Pw[k] = Tw[k] + cA*Aw[k]; Pv[k] = Tv[k] + cA*Av[k]; }
        // lane 8: Coriolis injection using lane 7's NEW V
        float Vw[3], Vv[3];
#pragma unroll
        for (int k = 0; k < 3; k++) {
          Vw[k] = __shfl(Pw[k], base + 7, 64);
          Vv[k] = __shfl(Pv[k], base + 7, 64);
        }
        float c1[3], c2[3], c3[3];
        cross3(c1, Vw, Aw);
        cross3(c2, Vv, Aw);
        cross3(c3, Vw, Av);
        float c8 = (r == 8) ? dqi : 0.f;
#pragma unroll
        for (int k = 0; k < 3; k++) { Pw[k] += c8*c1[k]; Pv[k] += c8*(c2[k]+c3[k]); }
#pragma unroll
        for (int k = 0; k < 3; k++) { Phw[i][k] = Pw[k]; Phv[i][k] = Pv[k]; }
      }
      // backward
      float Fw[3] = {0.f, 0.f, 0.f}, Fv[3] = {0.f, 0.f, 0.f};
#pragma unroll
      for (int i = NDOF-1; i >= 0; i--) {
        if (i < NDOF-1) {
          const int jn = i + 1;
          float R[9], Bm[9];
#pragma unroll
          for (int k = 0; k < 9; k++) {
            R[k]  = sRB[(jn*18 +     k)*EP + e];
            Bm[k] = sRB[(jn*18 + 9 + k)*EP + e];
          }
          float nw[3], nv[3], t[3];
          mat3T_vec(nw, R, Fw);
          mat3T_vec(t, Bm, Fv);
          nw[0] += t[0]; nw[1] += t[1]; nw[2] += t[2];
          mat3T_vec(nv, R, Fv);
          Fw[0] = nw[0]; Fw[1] = nw[1]; Fw[2] = nw[2];
          Fv[0] = nv[0]; Fv[1] = nv[1]; Fv[2] = nv[2];
        }
        float gx = sG[i][0], gy = sG[i][1], gz = sG[i][2], m_ = sG[i][3];
        // G * (own history): columns -> G*X ; lane 7 -> G*V
        float aw[3] = {gx*Phw[i][0], gy*Phw[i][1], gz*Phw[i][2]};
        float av[3] = {m_*Phv[i][0], m_*Phv[i][1], m_*Phv[i][2]};
        // lane 7 extras: G*Vd (history from lane 8) + crosses from own V
        float Dw[3], Dv[3];
#pragma unroll
        for (int k = 0; k < 3; k++) {
          Dw[k] = __shfl(Phw[i][k], base + 8, 64);
          Dv[k] = __shfl(Phv[i][k], base + 8, 64);
        }
        float GDw[3] = {gx*Dw[0], gy*Dw[1], gz*Dw[2]};
        float GDv[3] = {m_*Dv[0], m_*Dv[1], m_*Dv[2]};
        float x1[3], x2[3], x3[3];
        cross3(x1, Phw[i], aw);   // Vw x GVw   (lane-7 semantics)
        cross3(x2, Phv[i], av);   // Vv x GVv
        cross3(x3, Phw[i], av);   // Vw x GVv
        const bool l7 = (r == 7);
#pragma unroll
        for (int k = 0; k < 3; k++) {
          Fw[k] += l7 ? (GDw[k] + x1[k] + x2[k]) : aw[k];
          Fv[k] += l7 ? (GDv[k] + x3[k])         : av[k];
        }
        float val = Fw[0]*sA[i][0] + Fw[1]*sA[i][1] + Fw[2]*sA[i][2]
                  + Fv[0]*sA[i][3] + Fv[1]*sA[i][4] + Fv[2]*sA[i][5];
        if (r < NDOF && i >= r) MllL[(i*(i+1)/2 + r)*EP + e] = val;
        if (r == 7) bias_reg[i] = val;
      }
    }
    __syncthreads();

    // ---- (D) Cholesky solve, lane r==7 ----
    if (r == 7) {
      float Lm[28];
#pragma unroll
      for (int idx = 0; idx < 28; idx++) Lm[idx] = MllL[idx*EP + e];
      float y[NDOF];
#pragma unroll
      for (int i = 0; i < NDOF; i++) y[i] = tauL[i*EP + e] - bias_reg[i];
#pragma unroll
      for (int k = 0; k < NDOF; k++) {
        float d = Lm[k*(k+1)/2 + k];
#pragma unroll
        for (int m2 = 0; m2 < k; m2++) { float l = Lm[k*(k+1)/2 + m2]; d -= l*l; }
        d = sqrtf(d);
        Lm[k*(k+1)/2 + k] = d;
        float inv = 1.0f / d;
#pragma unroll
        for (int i = k+1; i < NDOF; i++) {
          float s = Lm[i*(i+1)/2 + k];
#pragma unroll
          for (int m2 = 0; m2 < k; m2++) s -= Lm[i*(i+1)/2 + m2]*Lm[k*(k+1)/2 + m2];
          Lm[i*(i+1)/2 + k] = s * inv;
        }
      }
#pragma unroll
      for (int i = 0; i < NDOF; i++) {
        float s = y[i];
#pragma unroll
        for (int m2 = 0; m2 < i; m2++) s -= Lm[i*(i+1)/2 + m2]*y[m2];
        y[i] = s / Lm[i*(i+1)/2 + i];
      }
      float qac[NDOF];
#pragma unroll
      for (int i = NDOF-1; i >= 0; i--) {
        float s = y[i];
#pragma unroll
        for (int m2 = i+1; m2 < NDOF; m2++) s -= Lm[m2*(m2+1)/2 + i]*qac[m2];
        qac[i] = s / Lm[i*(i+1)/2 + i];
      }
#pragma unroll
      for (int i = 0; i < NDOF; i++) qaccL[i*EP + e] = qac[i];
    }
    __syncthreads();

    // ---- (E) RK4 stage update, lanes r<7 ----
    if (r < NDOF) {
      float a = qaccL[r*EP + e];
      float w = (st == 0 || st == 3) ? 1.0f : 2.0f;
      accq += w * dqs;
      accd += w * a;
      if (st < 3) {
        float c = (st == 2) ? HSTEP : 0.5f*HSTEP;
        qs  = q0  + c * dqs;
        dqs = dq0 + c * a;
      }
    }
    // next stage's post-(A) barrier orders qaccL (E read -> next D write) and
    // sRB (BC read -> next A write); MllL WAR covered by post-(BC) barrier.
  }

  const float h6 = HSTEP / 6.0f;
  if (r < NDOF) {
    float qf = wrap_pi(q0 + h6*accq);
    float v  = dq0 + h6*accd;
    float dqf = fminf(fmaxf(v, -MAX_VEL), MAX_VEL);
    qfL[r*EP + e] = qf;
    g_out_state[b*14 + r]     = qf;
    g_out_state[b*14 + 7 + r] = dqf;
  }
  __syncthreads();

  if (r == 7) {
    float Tr9[9] = {1,0,0, 0,1,0, 0,0,1};
    float Tp[3] = {0,0,0};
#pragma unroll
    for (int i = 0; i < NDOF; i++) {
      float MRl[9];
#pragma unroll
      for (int k = 0; k < 9; k++) MRl[k] = sMR[i][k];
      float Mpl[3] = {sMp[i][0], sMp[i][1], sMp[i][2]};
      float R1[9];
      mat3_mul(R1, Tr9, MRl);
      float p1[3];
      mat3_vec(p1, Tr9, Mpl);
      p1[0] += Tp[0]; p1[1] += Tp[1]; p1[2] += Tp[2];
      float Ai[6];
#pragma unroll
      for (int k = 0; k < 6; k++) Ai[k] = sA[i][k];
      float Re[9], pe[3];
      exp_se3(Ai, qfL[i*EP + e], Re, pe);
      mat3_mul(Tr9, R1, Re);
      mat3_vec(Tp, R1, pe);
      Tp[0] += p1[0]; Tp[1] += p1[1]; Tp[2] += p1[2];
    }
    float Mp7[3] = {sMp[7][0], sMp[7][1], sMp[7][2]};
    float pf[3];
    mat3_vec(pf, Tr9, Mp7);
    g_out_ee[b*2 + 0] = pf[0] + Tp[0];
    g_out_ee[b*2 + 1] = pf[1] + Tp[1];
  }
}

extern "C" void kernel_launch(void* const* d_in, const int* in_sizes, int n_in,
                              void* d_out, int out_size, void* d_ws, size_t ws_size,
                              hipStream_t stream) {
  const float* state  = (const float*)d_in[0];  // (16384,14)
  const float* action = (const float*)d_in[1];  // (16384,7)
  const float* M      = (const float*)d_in[2];  // (8,4,4)
  const float* A      = (const float*)d_in[3];  // (7,6)
  const float* G      = (const float*)d_in[4];  // (7,4)
  const float* grav   = (const float*)d_in[5];  // (3,)
  float* out_state = (float*)d_out;                       // (16384,14)
  float* out_ee    = (float*)d_out + (size_t)BATCH * 14;  // (16384,2)

  arm_rk4_kernel<<<BATCH / EPB, BLOCK, 0, stream>>>(
      state, action, M, A, G, grav, out_state, out_ee);
}

// Round 9
// 103.125 us; speedup vs baseline: 1.5526x; 1.3313x over previous
//
#include <hip/hip_runtime.h>
#include <math.h>

#define BLOCK 64
#define BATCH 16384
#define EPB 8      // elements per block: 8 lanes per element
#define EP 9       // element-dim stride (8 elems + 1 pad) for per-element LDS
#define NDOF 7
#define ACTION_RANGE 50.0f
#define MAX_VEL 20.0f
#define HSTEP 0.1f

__device__ __forceinline__ void mat3_mul(float* C, const float* A, const float* B) {
#pragma unroll
  for (int r = 0; r < 3; r++) {
#pragma unroll
    for (int c = 0; c < 3; c++) {
      C[r*3+c] = A[r*3+0]*B[0*3+c] + A[r*3+1]*B[1*3+c] + A[r*3+2]*B[2*3+c];
    }
  }
}

__device__ __forceinline__ void mat3_vec(float* y, const float* A, const float* x) {
#pragma unroll
  for (int r = 0; r < 3; r++)
    y[r] = A[r*3+0]*x[0] + A[r*3+1]*x[1] + A[r*3+2]*x[2];
}

__device__ __forceinline__ void mat3T_vec(float* y, const float* A, const float* x) {
#pragma unroll
  for (int r = 0; r < 3; r++)
    y[r] = A[0*3+r]*x[0] + A[1*3+r]*x[1] + A[2*3+r]*x[2];
}

__device__ __forceinline__ void cross3(float* y, const float* a, const float* b) {
  y[0] = a[1]*b[2] - a[2]*b[1];
  y[1] = a[2]*b[0] - a[0]*b[2];
  y[2] = a[0]*b[1] - a[1]*b[0];
}

// R = I + s*W + (1-c)*W^2 ; p = (th*I + (1-c)*W + (th-s)*W^2) v
__device__ __forceinline__ void exp_se3(const float* A6, float th, float* R, float* p) {
  float w0 = A6[0], w1 = A6[1], w2 = A6[2];
  float s = __sinf(th);
  float c = __cosf(th);
  float omc = 1.0f - c, tms = th - s;
  float W[9]  = {0.f, -w2, w1,  w2, 0.f, -w0,  -w1, w0, 0.f};
  float W2[9];
  mat3_mul(W2, W, W);
#pragma unroll
  for (int k = 0; k < 9; k++) R[k] = s*W[k] + omc*W2[k];
  R[0] += 1.f; R[4] += 1.f; R[8] += 1.f;
  float G[9];
#pragma unroll
  for (int k = 0; k < 9; k++) G[k] = omc*W[k] + tms*W2[k];
  G[0] += th; G[4] += th; G[8] += th;
  mat3_vec(p, G, A6 + 3);
}

// python-style mod: a - floor(a/y)*y  (result in [0,y))
__device__ __forceinline__ float wrap_pi(float x) {
  const float PI_F   = 3.14159265358979323846f;
  const float TWO_PI = 6.28318530717958647692f;
  float a = x + PI_F;
  float r = a - floorf(a * (1.0f / TWO_PI)) * TWO_PI;
  return r - PI_F;
}

// R9: 8 lanes per element (e = tid>>3, r = tid&7), 2048 blocks.
// R8 resolved the spill mystery (VGPR 68, hbm 2.4 MB) and is VALU/latency
// bound with only ~9/16 lanes useful. R9 doubles elements-per-wave-stream:
// roles r<7 = mass columns, lane 7 = BOTH V and Vd (Vd injection uses own
// updated V -> no shuffles for V). Vd history in LDS (lane-7 write) to keep
// VGPR under the 128 tier (R4 lesson: never let both histories live in regs).
__global__ __launch_bounds__(BLOCK, 2) void arm_rk4_kernel(
    const float* __restrict__ g_state, const float* __restrict__ g_action,
    const float* __restrict__ g_M, const float* __restrict__ g_A,
    const float* __restrict__ g_G, const float* __restrict__ g_grav,
    float* __restrict__ g_out_state, float* __restrict__ g_out_ee)
{
  __shared__ float sMR[8][9];
  __shared__ float sMp[8][3];
  __shared__ float sIR[7][9];
  __shared__ float sIp[7][3];
  __shared__ float sA[7][6];
  __shared__ float sG[7][4];
  __shared__ float sg[3];
  __shared__ float sRB[7*18*EP];   // per joint: R[9], B[9]  (AdT = [[R,0],[B,R]])
  __shared__ float sQh[7*6*EP];    // per joint: Vd (lane-7 history)
  __shared__ float tauL[NDOF*EP];
  __shared__ float qaccL[NDOF*EP];
  __shared__ float qfL[NDOF*EP];
  __shared__ float MllL[28*EP];

  const int tid  = threadIdx.x;
  const int e    = tid >> 3;      // element slot 0..7
  const int r    = tid & 7;       // role 0..7
  const int base = tid & 0x38;    // first lane of this element group
  const int b    = blockIdx.x * EPB + e;

  if (tid < 8) {
    const float* Mi = g_M + tid*16;
    float a1[3] = {Mi[0], Mi[4], Mi[8]};
    float a2[3] = {Mi[1], Mi[5], Mi[9]};
    float p[3]  = {Mi[3], Mi[7], Mi[11]};
    float n1 = sqrtf(a1[0]*a1[0] + a1[1]*a1[1] + a1[2]*a1[2]);
    float b1[3] = {a1[0]/n1, a1[1]/n1, a1[2]/n1};
    float d = a2[0]*b1[0] + a2[1]*b1[1] + a2[2]*b1[2];
    float a2o[3] = {a2[0]-d*b1[0], a2[1]-d*b1[1], a2[2]-d*b1[2]};
    float n2 = sqrtf(a2o[0]*a2o[0] + a2o[1]*a2o[1] + a2o[2]*a2o[2]);
    float b2[3] = {a2o[0]/n2, a2o[1]/n2, a2o[2]/n2};
    float b3[3];
    cross3(b3, b1, b2);
    float R[9] = {b1[0], b2[0], b3[0],  b1[1], b2[1], b3[1],  b1[2], b2[2], b3[2]};
#pragma unroll
    for (int k = 0; k < 9; k++) sMR[tid][k] = R[k];
    sMp[tid][0] = p[0]; sMp[tid][1] = p[1]; sMp[tid][2] = p[2];
    if (tid < 7) {
#pragma unroll
      for (int rr = 0; rr < 3; rr++)
#pragma unroll
        for (int cc = 0; cc < 3; cc++) sIR[tid][rr*3+cc] = R[cc*3+rr];
#pragma unroll
      for (int rr = 0; rr < 3; rr++)
        sIp[tid][rr] = -(R[0*3+rr]*p[0] + R[1*3+rr]*p[1] + R[2*3+rr]*p[2]);
      const float* Ar = g_A + tid*6;
      float nw = sqrtf(Ar[0]*Ar[0] + Ar[1]*Ar[1] + Ar[2]*Ar[2]);
      sA[tid][0] = Ar[0]/nw; sA[tid][1] = Ar[1]/nw; sA[tid][2] = Ar[2]/nw;
      sA[tid][3] = Ar[3];    sA[tid][4] = Ar[4];    sA[tid][5] = Ar[5];
      sG[tid][0] = fabsf(g_G[tid*4+0]);
      sG[tid][1] = fabsf(g_G[tid*4+1]);
      sG[tid][2] = fabsf(g_G[tid*4+2]);
      sG[tid][3] = fabsf(g_G[tid*4+3]);
    }
  }
  if (tid == 0) { sg[0] = g_grav[0]; sg[1] = g_grav[1]; sg[2] = g_grav[2]; }

  float q0 = 0.f, dq0 = 0.f, qs = 0.f, dqs = 0.f;
  float accq = 0.f, accd = 0.f;
  if (r < NDOF) {
    q0  = g_state[b*14 + r];
    dq0 = g_state[b*14 + 7 + r];
    float tau = g_action[b*7 + r] * ACTION_RANGE;
    qs = q0; dqs = dq0;
    tauL[r*EP + e] = tau;
  }
  __syncthreads();

#pragma unroll 1
  for (int st = 0; st < 4; st++) {
    float bias_reg[NDOF];   // valid on lane r==7

    // ---- (A) adjoint of joint r, lanes r<7 ----
    if (r < NDOF) {
      float Ai[6];
#pragma unroll
      for (int k = 0; k < 6; k++) Ai[k] = sA[r][k];
      float Re[9], pe[3];
      exp_se3(Ai, -qs, Re, pe);
      float IRl[9];
#pragma unroll
      for (int k = 0; k < 9; k++) IRl[k] = sIR[r][k];
      float Tr9[9];
      mat3_mul(Tr9, Re, IRl);
      float Ipl[3] = {sIp[r][0], sIp[r][1], sIp[r][2]};
      float Tp[3];
      mat3_vec(Tp, Re, Ipl);
      Tp[0] += pe[0]; Tp[1] += pe[1]; Tp[2] += pe[2];
      float Bm[9];
#pragma unroll
      for (int c = 0; c < 3; c++) {
        Bm[0*3+c] = -Tp[2]*Tr9[1*3+c] + Tp[1]*Tr9[2*3+c];
        Bm[1*3+c] =  Tp[2]*Tr9[0*3+c] - Tp[0]*Tr9[2*3+c];
        Bm[2*3+c] = -Tp[1]*Tr9[0*3+c] + Tp[0]*Tr9[1*3+c];
      }
#pragma unroll
      for (int k = 0; k < 9; k++) {
        sRB[(r*18 +     k)*EP + e] = Tr9[k];
        sRB[(r*18 + 9 + k)*EP + e] = Bm[k];
      }
    }
    __syncthreads();

    // ---- (BC) fused forward+backward sweep, ALL 8 lanes ----
    // lane r<7 : P = mass column r (inject A_r at joint r)
    // lane 7   : P = V (inject dq_i*A_i) AND Q = Vd (gravity init; inject
    //            dq_i*ad(V)A_i with own updated V). Vd history -> LDS.
    {
      float Phw[NDOF][3], Phv[NDOF][3];
      float Pw[3] = {0.f, 0.f, 0.f}, Pv[3] = {0.f, 0.f, 0.f};
      float Qw[3] = {0.f, 0.f, 0.f}, Qv[3] = {0.f, 0.f, 0.f};
      if (r == 7) { Qv[0] = -sg[0]; Qv[1] = -sg[1]; Qv[2] = -sg[2]; }
#pragma unroll
      for (int i = 0; i < NDOF; i++) {
        float R[9], Bm[9];
#pragma unroll
        for (int k = 0; k < 9; k++) {
          R[k]  = sRB[(i*18 +     k)*EP + e];
          Bm[k] = sRB[(i*18 + 9 + k)*EP + e];
        }
        float dqi = __shfl(dqs, base + i, 64);
        float Aw[3] = {sA[i][0], sA[i][1], sA[i][2]};
        float Av[3] = {sA[i][3], sA[i][4], sA[i][5]};
        // P
        float Tw[3], Tv[3], t2[3];
        mat3_vec(Tw, R,  Pw);
        mat3_vec(Tv, Bm, Pw);
        mat3_vec(t2, R,  Pv);
        float cA = (r == i) ? 1.f : ((r == 7) ? dqi : 0.f);
#pragma unroll
        for (int k = 0; k < 3; k++) {
          Pw[k] = Tw[k] + cA*Aw[k];
          Pv[k] = Tv[k] + t2[k] + cA*Av[k];
        }
        // Q = AdT*Q + dq_i * ad(P)A_i   (meaningful on lane 7 only)
        float Uw[3], Uv[3], u2[3];
        mat3_vec(Uw, R,  Qw);
        mat3_vec(Uv, Bm, Qw);
        mat3_vec(u2, R,  Qv);
        float c1[3], c2[3], c3[3];
        cross3(c1, Pw, Aw);
        cross3(c2, Pv, Aw);
        cross3(c3, Pw, Av);
        float c8 = (r == 7) ? dqi : 0.f;
#pragma unroll
        for (int k = 0; k < 3; k++) {
          Qw[k] = Uw[k] + c8*c1[k];
          Qv[k] = Uv[k] + u2[k] + c8*(c2[k]+c3[k]);
        }
        if (r == 7) {
#pragma unroll
          for (int k = 0; k < 3; k++) {
            sQh[(i*6 +     k)*EP + e] = Qw[k];
            sQh[(i*6 + 3 + k)*EP + e] = Qv[k];
          }
        }
#pragma unroll
        for (int k = 0; k < 3; k++) { Phw[i][k] = Pw[k]; Phv[i][k] = Pv[k]; }
      }
      // backward
      float Fw[3] = {0.f, 0.f, 0.f}, Fv[3] = {0.f, 0.f, 0.f};
#pragma unroll
      for (int i = NDOF-1; i >= 0; i--) {
        if (i < NDOF-1) {
          const int jn = i + 1;
          float R[9], Bm[9];
#pragma unroll
          for (int k = 0; k < 9; k++) {
            R[k]  = sRB[(jn*18 +     k)*EP + e];
            Bm[k] = sRB[(jn*18 + 9 + k)*EP + e];
          }
          float nw[3], nv[3], t[3];
          mat3T_vec(nw, R, Fw);
          mat3T_vec(t, Bm, Fv);
          nw[0] += t[0]; nw[1] += t[1]; nw[2] += t[2];
          mat3T_vec(nv, R, Fv);
          Fw[0] = nw[0]; Fw[1] = nw[1]; Fw[2] = nw[2];
          Fv[0] = nv[0]; Fv[1] = nv[1]; Fv[2] = nv[2];
        }
        float gx = sG[i][0], gy = sG[i][1], gz = sG[i][2], m_ = sG[i][3];
        // own G-term: columns -> G*X ; lane 7 -> G*V
        float aw[3] = {gx*Phw[i][0], gy*Phw[i][1], gz*Phw[i][2]};
        float av[3] = {m_*Phv[i][0], m_*Phv[i][1], m_*Phv[i][2]};
        // lane 7 extras: G*Vd (LDS history) + ad(V)^T crosses from own V
        float Dw[3], Dv[3];
#pragma unroll
        for (int k = 0; k < 3; k++) {
          Dw[k] = sQh[(i*6 +     k)*EP + e];
          Dv[k] = sQh[(i*6 + 3 + k)*EP + e];
        }
        float GDw[3] = {gx*Dw[0], gy*Dw[1], gz*Dw[2]};
        float GDv[3] = {m_*Dv[0], m_*Dv[1], m_*Dv[2]};
        float x1[3], x2[3], x3[3];
        cross3(x1, Phw[i], aw);   // Vw x GVw  (lane-7 semantics)
        cross3(x2, Phv[i], av);   // Vv x GVv
        cross3(x3, Phw[i], av);   // Vw x GVv
        const bool l7 = (r == 7);
#pragma unroll
        for (int k = 0; k < 3; k++) {
          Fw[k] += l7 ? (GDw[k] + x1[k] + x2[k]) : aw[k];
          Fv[k] += l7 ? (GDv[k] + x3[k])         : av[k];
        }
        float val = Fw[0]*sA[i][0] + Fw[1]*sA[i][1] + Fw[2]*sA[i][2]
                  + Fv[0]*sA[i][3] + Fv[1]*sA[i][4] + Fv[2]*sA[i][5];
        if (r < NDOF && i >= r) MllL[(i*(i+1)/2 + r)*EP + e] = val;
        if (r == 7) bias_reg[i] = val;
      }
    }
    __syncthreads();

    // ---- (D) Cholesky solve, lane r==7 (reciprocal-cached) ----
    if (r == 7) {
      float Lm[28], invd[NDOF];
#pragma unroll
      for (int idx = 0; idx < 28; idx++) Lm[idx] = MllL[idx*EP + e];
      float y[NDOF];
#pragma unroll
      for (int i = 0; i < NDOF; i++) y[i] = tauL[i*EP + e] - bias_reg[i];
#pragma unroll
      for (int k = 0; k < NDOF; k++) {
        float d = Lm[k*(k+1)/2 + k];
#pragma unroll
        for (int m2 = 0; m2 < k; m2++) { float l = Lm[k*(k+1)/2 + m2]; d -= l*l; }
        d = sqrtf(d);
        Lm[k*(k+1)/2 + k] = d;
        float inv = 1.0f / d;
        invd[k] = inv;
#pragma unroll
        for (int i = k+1; i < NDOF; i++) {
          float s = Lm[i*(i+1)/2 + k];
#pragma unroll
          for (int m2 = 0; m2 < k; m2++) s -= Lm[i*(i+1)/2 + m2]*Lm[k*(k+1)/2 + m2];
          Lm[i*(i+1)/2 + k] = s * inv;
        }
      }
#pragma unroll
      for (int i = 0; i < NDOF; i++) {
        float s = y[i];
#pragma unroll
        for (int m2 = 0; m2 < i; m2++) s -= Lm[i*(i+1)/2 + m2]*y[m2];
        y[i] = s * invd[i];
      }
      float qac[NDOF];
#pragma unroll
      for (int i = NDOF-1; i >= 0; i--) {
        float s = y[i];
#pragma unroll
        for (int m2 = i+1; m2 < NDOF; m2++) s -= Lm[m2*(m2+1)/2 + i]*qac[m2];
        qac[i] = s * invd[i];
      }
#pragma unroll
      for (int i = 0; i < NDOF; i++) qaccL[i*EP + e] = qac[i];
    }
    __syncthreads();

    // ---- (E) RK4 stage update, lanes r<7 ----
    if (r < NDOF) {
      float a = qaccL[r*EP + e];
      float w = (st == 0 || st == 3) ? 1.0f : 2.0f;
      accq += w * dqs;
      accd += w * a;
      if (st < 3) {
        float c = (st == 2) ? HSTEP : 0.5f*HSTEP;
        qs  = q0  + c * dqs;
        dqs = dq0 + c * a;
      }
    }
  }

  const float h6 = HSTEP / 6.0f;
  if (r < NDOF) {
    float qf = wrap_pi(q0 + h6*accq);
    float v  = dq0 + h6*accd;
    float dqf = fminf(fmaxf(v, -MAX_VEL), MAX_VEL);
    qfL[r*EP + e] = qf;
    g_out_state[b*14 + r]     = qf;
    g_out_state[b*14 + 7 + r] = dqf;
  }
  __syncthreads();

  if (r == 7) {
    float Tr9[9] = {1,0,0, 0,1,0, 0,0,1};
    float Tp[3] = {0,0,0};
#pragma unroll
    for (int i = 0; i < NDOF; i++) {
      float MRl[9];
#pragma unroll
      for (int k = 0; k < 9; k++) MRl[k] = sMR[i][k];
      float Mpl[3] = {sMp[i][0], sMp[i][1], sMp[i][2]};
      float R1[9];
      mat3_mul(R1, Tr9, MRl);
      float p1[3];
      mat3_vec(p1, Tr9, Mpl);
      p1[0] += Tp[0]; p1[1] += Tp[1]; p1[2] += Tp[2];
      float Ai[6];
#pragma unroll
      for (int k = 0; k < 6; k++) Ai[k] = sA[i][k];
      float Re[9], pe[3];
      exp_se3(Ai, qfL[i*EP + e], Re, pe);
      mat3_mul(Tr9, R1, Re);
      mat3_vec(Tp, R1, pe);
      Tp[0] += p1[0]; Tp[1] += p1[1]; Tp[2] += p1[2];
    }
    float Mp7[3] = {sMp[7][0], sMp[7][1], sMp[7][2]};
    float pf[3];
    mat3_vec(pf, Tr9, Mp7);
    g_out_ee[b*2 + 0] = pf[0] + Tp[0];
    g_out_ee[b*2 + 1] = pf[1] + Tp[1];
  }
}

extern "C" void kernel_launch(void* const* d_in, const int* in_sizes, int n_in,
                              void* d_out, int out_size, void* d_ws, size_t ws_size,
                              hipStream_t stream) {
  const float* state  = (const float*)d_in[0];  // (16384,14)
  const float* action = (const float*)d_in[1];  // (16384,7)
  const float* M      = (const float*)d_in[2];  // (8,4,4)
  const float* A      = (const float*)d_in[3];  // (7,6)
  const float* G      = (const float*)d_in[4];  // (7,4)
  const float* grav   = (const float*)d_in[5];  // (3,)
  float* out_state = (float*)d_out;                       // (16384,14)
  float* out_ee    = (float*)d_out + (size_t)BATCH * 14;  // (16384,2)

  arm_rk4_kernel<<<BATCH / EPB, BLOCK, 0, stream>>>(
      state, action, M, A, G, grav, out_state, out_ee);
}